// Round 8
// baseline (382.478 us; speedup 1.0000x reference)
//
#include <hip/hip_runtime.h>
#include <hip/hip_bf16.h>
#include <stdint.h>

#define NH 16
#define NKV 8
#define HD 128
#define BB 4
#define SS 1024
#define CTXL 2048
#define LT 3072
#define HID 2048
#define QKVN 4096
#define MROWS 4096

typedef __hip_bfloat16 bf16;
using f32x4 = __attribute__((ext_vector_type(4))) float;
using s16x8 = __attribute__((ext_vector_type(8))) short;

#define MFMA(a, b, c) __builtin_amdgcn_mfma_f32_16x16x32_bf16((a), (b), (c), 0, 0, 0)

__device__ __forceinline__ void gload_lds16(const void* g, void* l) {
  __builtin_amdgcn_global_load_lds((const __attribute__((address_space(1))) void*)g,
                                   (__attribute__((address_space(3))) void*)l, 16, 0, 0);
}

__device__ __forceinline__ void store_bf8(bf16* dst, const float* f) {
  bf16 tmp[8];
#pragma unroll
  for (int j = 0; j < 8; ++j) tmp[j] = __float2bfloat16(f[j]);
  __builtin_memcpy((void*)dst, (const void*)tmp, 16);
}

// ---------------- prep kernels ----------------

__global__ void cvt_bf16(const float* __restrict__ in, bf16* __restrict__ out) {
  size_t tid = (size_t)blockIdx.x * 256 + threadIdx.x;  // one thread per 8 elems
  const float4* p = (const float4*)(in + tid * 8);
  float4 a = p[0], b = p[1];
  float f[8] = {a.x, a.y, a.z, a.w, b.x, b.y, b.z, b.w};
  store_bf8(out + tid * 8, f);
}

// out[c][r] = (bf16) in[r][c]
__global__ void transpose_cvt(const float* __restrict__ in, bf16* __restrict__ out,
                              int R, int C) {
  __shared__ float tile[32][33];
  int c0 = blockIdx.x * 32, r0 = blockIdx.y * 32;
  int tx = threadIdx.x & 31, ty = threadIdx.x >> 5;
#pragma unroll
  for (int i = 0; i < 32; i += 8)
    tile[ty + i][tx] = in[(size_t)(r0 + ty + i) * C + c0 + tx];
  __syncthreads();
#pragma unroll
  for (int i = 0; i < 32; i += 8)
    out[(size_t)(c0 + ty + i) * R + r0 + tx] = __float2bfloat16(tile[tx][ty + i]);
}

// ctx_k [b][l][h][d] f32 -> K_full [b][h][l][d] bf16 (l < CTXL)
__global__ void ctxk_copy(const float* __restrict__ ck, bf16* __restrict__ Kf) {
  int tid = blockIdx.x * 256 + threadIdx.x;
  int d8 = tid & 15, l = (tid >> 4) & 2047, h = (tid >> 15) & 7, b = tid >> 18;
  const float* s = ck + (((size_t)b * CTXL + l) * NKV + h) * HD + d8 * 8;
  const float4* p = (const float4*)s;
  float4 a = p[0], bb = p[1];
  float f[8] = {a.x, a.y, a.z, a.w, bb.x, bb.y, bb.z, bb.w};
  store_bf8(Kf + (((size_t)(b * NKV + h)) * LT + l) * HD + d8 * 8, f);
}

// ctx_v [b][l][h][d] f32 -> V_T [b][h][d][l] bf16 (l < CTXL)
__global__ void ctxv_transpose(const float* __restrict__ cv, bf16* __restrict__ Vt) {
  __shared__ float tile[32][33];
  int l0 = blockIdx.x * 32, d0 = blockIdx.y * 32;
  int b = blockIdx.z >> 3, h = blockIdx.z & 7;
  int tx = threadIdx.x & 31, ty = threadIdx.x >> 5;
#pragma unroll
  for (int i = 0; i < 32; i += 8)
    tile[ty + i][tx] = cv[(((size_t)b * CTXL + l0 + ty + i) * NKV + h) * HD + d0 + tx];
  __syncthreads();
#pragma unroll
  for (int i = 0; i < 32; i += 8)
    Vt[(((size_t)(b * NKV + h)) * HD + d0 + ty + i) * LT + l0 + tx] =
        __float2bfloat16(tile[tx][ty + i]);
}

// qkv v-slice -> V_T tail (l = CTXL + s)
__global__ void vt_from_qkv(const bf16* __restrict__ qkv, bf16* __restrict__ Vt) {
  __shared__ float tile[32][33];
  int s0 = blockIdx.x * 32, d0 = blockIdx.y * 32;
  int b = blockIdx.z >> 3, h = blockIdx.z & 7;
  int tx = threadIdx.x & 31, ty = threadIdx.x >> 5;
#pragma unroll
  for (int i = 0; i < 32; i += 8)
    tile[ty + i][tx] = __bfloat162float(
        qkv[((size_t)b * SS + s0 + ty + i) * QKVN + 3072 + h * HD + d0 + tx]);
  __syncthreads();
#pragma unroll
  for (int i = 0; i < 32; i += 8)
    Vt[(((size_t)(b * NKV + h)) * HD + d0 + ty + i) * LT + CTXL + s0 + tx] =
        __float2bfloat16(tile[tx][ty + i]);
}

__global__ void rope_table(const int* __restrict__ pid, float* __restrict__ cosT,
                           float* __restrict__ sinT) {
  int tid = blockIdx.x * 256 + threadIdx.x;  // S*64
  int j = tid & 63, s = tid >> 6;
  int sec = (j < 8) ? 0 : (j < 16) ? 1 : (j < 40) ? 2 : 3;
  float pos = (float)pid[sec * SS + s];
  float inv = __expf(-(float)j * 0.14391156831212787f);  // ln(10000)/64
  float a = pos * inv;
  cosT[tid] = cosf(a);
  sinT[tid] = sinf(a);
}

__global__ void rope_q(const bf16* __restrict__ qkv, const float* __restrict__ cosT,
                       const float* __restrict__ sinT, bf16* __restrict__ Q) {
  int tid = blockIdx.x * 256 + threadIdx.x;
  int j = tid & 63, h = (tid >> 6) & 15, s = (tid >> 10) & 1023, b = tid >> 20;
  const bf16* src = qkv + ((size_t)b * SS + s) * QKVN + h * HD;
  float x1 = __bfloat162float(src[j]), x2 = __bfloat162float(src[j + 64]);
  float c = cosT[s * 64 + j], sn = sinT[s * 64 + j];
  bf16* dst = Q + (((size_t)(b * NH + h)) * SS + s) * HD;
  dst[j] = __float2bfloat16(x1 * c - x2 * sn);
  dst[j + 64] = __float2bfloat16(x2 * c + x1 * sn);
}

__global__ void rope_k(const bf16* __restrict__ qkv, const float* __restrict__ cosT,
                       const float* __restrict__ sinT, bf16* __restrict__ Kf) {
  int tid = blockIdx.x * 256 + threadIdx.x;
  int j = tid & 63, h = (tid >> 6) & 7, s = (tid >> 9) & 1023, b = tid >> 19;
  const bf16* src = qkv + ((size_t)b * SS + s) * QKVN + 2048 + h * HD;
  float x1 = __bfloat162float(src[j]), x2 = __bfloat162float(src[j + 64]);
  float c = cosT[s * 64 + j], sn = sinT[s * 64 + j];
  bf16* dst = Kf + (((size_t)(b * NKV + h)) * LT + CTXL + s) * HD;
  dst[j] = __float2bfloat16(x1 * c - x2 * sn);
  dst[j + 64] = __float2bfloat16(x2 * c + x1 * sn);
}

// ---------------- GEMM: C[M][N] = A[M][K] * BT[N][K]^T ----------------
// 256x128 tile, BK=64, 8 waves (4M x 2N), 512 threads. 3-buffer LDS (144 KB),
// prefetch depth 2, ONE barrier per K-tile, counted s_waitcnt vmcnt(6).
// XOR chunk swizzle both sides (rule 21).

template <typename OT>
__global__ __launch_bounds__(512, 1) void gemm_bt(const bf16* __restrict__ A,
                                                  const bf16* __restrict__ BT,
                                                  OT* __restrict__ C, int M, int N,
                                                  int K) {
  __shared__ __attribute__((aligned(16))) bf16 lA[3][256][64];  // 96 KB
  __shared__ __attribute__((aligned(16))) bf16 lB[3][128][64];  // 48 KB
  const int t = threadIdx.x;
  const int lane = t & 63, w = t >> 6;
  const int wr = w >> 1, wc = w & 1;
  const int lrow = lane & 15, kgrp = lane >> 4;
  const int rchk = lrow & 7;  // read-side swizzle bits (frag row & 7)
  const int m0 = blockIdx.y * 256, n0 = blockIdx.x * 128;
  const int srow = lane >> 3;              // 0..7: row within 8-row group
  const int schk = (lane & 7) ^ srow;      // pre-swizzled source chunk
  const f32x4 fz = {0.f, 0.f, 0.f, 0.f};
  f32x4 acc[4][4];
#pragma unroll
  for (int i = 0; i < 4; ++i)
#pragma unroll
    for (int j = 0; j < 4; ++j) acc[i][j] = fz;
  const int NTK = K >> 6;

#define GSTAGE(ib, kt)                                                      \
  do {                                                                      \
    _Pragma("unroll") for (int c = 0; c < 4; ++c) {                         \
      int ra = c * 64 + w * 8 + srow;                                       \
      gload_lds16(A + (size_t)(m0 + ra) * K + (kt)*64 + schk * 8,           \
                  &lA[ib][c * 64 + w * 8][0]);                              \
    }                                                                       \
    _Pragma("unroll") for (int c = 0; c < 2; ++c) {                         \
      int rb = c * 64 + w * 8 + srow;                                       \
      gload_lds16(BT + (size_t)(n0 + rb) * K + (kt)*64 + schk * 8,          \
                  &lB[ib][c * 64 + w * 8][0]);                              \
    }                                                                       \
  } while (0)

  GSTAGE(0, 0);
  GSTAGE(1, 1);
  int ib = 0;
  for (int kt = 0; kt < NTK; ++kt) {
    if (kt + 1 < NTK)
      asm volatile("s_waitcnt vmcnt(6) lgkmcnt(0)" ::: "memory");
    else
      asm volatile("s_waitcnt vmcnt(0) lgkmcnt(0)" ::: "memory");
    __builtin_amdgcn_s_barrier();
    __builtin_amdgcn_sched_barrier(0);
    if (kt + 2 < NTK) {
      int ib2 = ib + 2;
      if (ib2 >= 3) ib2 -= 3;
      GSTAGE(ib2, kt + 2);
    }
#pragma unroll
    for (int kk = 0; kk < 2; ++kk) {
      s16x8 af[4], bf[4];
#pragma unroll
      for (int i = 0; i < 4; ++i)
        af[i] = *(const s16x8*)&lA[ib][wr * 64 + i * 16 + lrow]
                                     [(((kk << 2) + kgrp) ^ rchk) * 8];
#pragma unroll
      for (int j = 0; j < 4; ++j)
        bf[j] = *(const s16x8*)&lB[ib][wc * 64 + j * 16 + lrow]
                                     [(((kk << 2) + kgrp) ^ rchk) * 8];
#pragma unroll
      for (int i = 0; i < 4; ++i)
#pragma unroll
        for (int j = 0; j < 4; ++j) acc[i][j] = MFMA(af[i], bf[j], acc[i][j]);
    }
    ++ib;
    if (ib >= 3) ib = 0;
  }
#undef GSTAGE

#pragma unroll
  for (int i = 0; i < 4; ++i)
#pragma unroll
    for (int j = 0; j < 4; ++j)
#pragma unroll
      for (int r = 0; r < 4; ++r) {
        int row = m0 + wr * 64 + i * 16 + kgrp * 4 + r;
        int col = n0 + wc * 64 + j * 16 + lrow;
        float v = acc[i][j][r];
        if constexpr (sizeof(OT) == 2)
          C[(size_t)row * N + col] = __float2bfloat16(v);
        else
          C[(size_t)row * N + col] = v;
      }
}

// ---------------- flash attention ----------------
// 256 q-rows/block, 8 waves x 32 rows (2 row-frags), KVBLK=64, swapped QK^T,
// lane-local softmax. NEW: 2-deep score pipeline (T15): per half-iteration,
// issue QK(t+1)->scNext (MFMA, unconsumed this half), then softmax(t) on
// scCur (VALU) overlaps the MFMA pipe, then P(t)->PV(t). Loop unrolled x2 so
// all buffer indices are compile-time (rule 20). Buffer safety: every LDS
// buffer's last read is barrier-separated from its next DMA write.
// XOR chunk swizzle both sides (rule 21): K chunk^(row&15), V chunk^(row&7).

#define PSTR 72  // P row stride in elements: 144B = 16B-aligned
#define NT 48    // LT / 64
// scale * log2(e): softmax computed in exp2 domain
#define SCALE2 0.1275174335919605f

__global__ __launch_bounds__(512, 2) void flash_attn(
    const bf16* __restrict__ Q, const bf16* __restrict__ Kf,
    const bf16* __restrict__ Vt, bf16* __restrict__ O) {
  __shared__ __attribute__((aligned(16))) bf16 Kl[2][64][128];      // 32 KB
  __shared__ __attribute__((aligned(16))) bf16 Vl[2][128][64];      // 32 KB
  __shared__ __attribute__((aligned(16))) bf16 P_lds[8][32][PSTR];  // 36 KB
  const int t = threadIdx.x, lane = t & 63, w = t >> 6;
  const int qb = blockIdx.x & 3, h = (blockIdx.x >> 2) & 15, b = blockIdx.x >> 6;
  const int hk = h >> 1;
  const int lrow = lane & 15, kgrp = lane >> 4;
  const bf16* Kp = Kf + (size_t)(b * NKV + hk) * LT * HD;
  const bf16* Vp = Vt + (size_t)(b * NKV + hk) * HD * LT;

  const bf16* Qp = Q + (((size_t)(b * NH + h)) * SS + qb * 256 + w * 32) * HD;
  s16x8 qf[2][4];
#pragma unroll
  for (int f = 0; f < 2; ++f)
#pragma unroll
    for (int kd = 0; kd < 4; ++kd)
      qf[f][kd] = *(const s16x8*)&Qp[(f * 16 + lrow) * HD + kd * 32 + kgrp * 8];

  const f32x4 fz = {0.f, 0.f, 0.f, 0.f};
  f32x4 acc[2][8];
#pragma unroll
  for (int f = 0; f < 2; ++f)
#pragma unroll
    for (int i = 0; i < 8; ++i) acc[f][i] = fz;
  float m_[2] = {-1e30f, -1e30f}, l_[2] = {0.f, 0.f};
  f32x4 scA[2][4], scB[2][4];

#define STAGE_K(buf, l0)                                                        \
  do {                                                                          \
    _Pragma("unroll") for (int c = 0; c < 2; ++c) {                             \
      int row = w * 8 + c * 4 + (lane >> 4);                                    \
      gload_lds16(Kp + (size_t)((l0) + row) * HD + ((lane & 15) ^ (row & 15)) * 8, \
                  &Kl[buf][w * 8 + c * 4][0]);                                  \
    }                                                                           \
  } while (0)
#define STAGE_V(buf, l0)                                                        \
  do {                                                                          \
    _Pragma("unroll") for (int c = 0; c < 2; ++c) {                             \
      int d = w * 16 + c * 8 + (lane >> 3);                                     \
      gload_lds16(Vp + (size_t)d * LT + (l0) + ((lane & 7) ^ (d & 7)) * 8,      \
                  &Vl[buf][w * 16 + c * 8][0]);                                 \
    }                                                                           \
  } while (0)

  // QK(tile in Kl[kbuf]) -> sc (results not consumed until next half)
  auto QK = [&](int kbuf, f32x4 (&sc)[2][4]) {
#pragma unroll
    for (int f = 0; f < 2; ++f)
#pragma unroll
      for (int cf = 0; cf < 4; ++cf) sc[f][cf] = fz;
#pragma unroll
    for (int cf = 0; cf < 4; ++cf)
#pragma unroll
      for (int kd = 0; kd < 4; ++kd) {
        s16x8 kb =
            *(const s16x8*)&Kl[kbuf][cf * 16 + lrow][((kd * 4 + kgrp) ^ lrow) * 8];
#pragma unroll
        for (int f = 0; f < 2; ++f) sc[f][cf] = MFMA(kb, qf[f][kd], sc[f][cf]);
      }
  };

  // softmax(sc) -> P -> PV from Vl[vbuf]
  auto SPV = [&](f32x4 (&sc)[2][4], int vbuf) {
    float mxv[2];
#pragma unroll
    for (int f = 0; f < 2; ++f) {
      float a0 = fmaxf(fmaxf(sc[f][0][0], sc[f][0][1]),
                       fmaxf(sc[f][0][2], sc[f][0][3]));
      float a1 = fmaxf(fmaxf(sc[f][1][0], sc[f][1][1]),
                       fmaxf(sc[f][1][2], sc[f][1][3]));
      float a2 = fmaxf(fmaxf(sc[f][2][0], sc[f][2][1]),
                       fmaxf(sc[f][2][2], sc[f][2][3]));
      float a3 = fmaxf(fmaxf(sc[f][3][0], sc[f][3][1]),
                       fmaxf(sc[f][3][2], sc[f][3][3]));
      float mx = fmaxf(fmaxf(a0, a1), fmaxf(a2, a3)) * SCALE2;
      mx = fmaxf(mx, __shfl_xor(mx, 16, 64));
      mx = fmaxf(mx, __shfl_xor(mx, 32, 64));
      mxv[f] = mx;
    }
    bool nb = (mxv[0] > m_[0] + 8.f) || (mxv[1] > m_[1] + 8.f);
    if (__any(nb)) {
#pragma unroll
      for (int f = 0; f < 2; ++f) {
        float mn = fmaxf(m_[f], mxv[f]);
        float so = exp2f(m_[f] - mn);
        m_[f] = mn;
        l_[f] *= so;
        float sob[4];
#pragma unroll
        for (int r = 0; r < 4; ++r) sob[r] = __shfl(so, kgrp * 4 + r, 16);
#pragma unroll
        for (int nd = 0; nd < 8; ++nd)
#pragma unroll
          for (int r = 0; r < 4; ++r) acc[f][nd][r] *= sob[r];
      }
    }
#pragma unroll
    for (int f = 0; f < 2; ++f) {
      float lp = 0.f;
#pragma unroll
      for (int cf = 0; cf < 4; ++cf) {
        bf16 pk[4];
#pragma unroll
        for (int r = 0; r < 4; ++r) {
          float p = exp2f(sc[f][cf][r] * SCALE2 - m_[f]);
          lp += p;
          pk[r] = __float2bfloat16(p);
        }
        __builtin_memcpy((void*)&P_lds[w][f * 16 + lrow][cf * 16 + kgrp * 4], pk, 8);
      }
      l_[f] += lp;
    }
    // per-wave LDS: in-wave write->read ordering via lgkmcnt, no barrier
    s16x8 pa[2][2];
#pragma unroll
    for (int f = 0; f < 2; ++f)
#pragma unroll
      for (int kc = 0; kc < 2; ++kc)
        pa[f][kc] = *(const s16x8*)&P_lds[w][f * 16 + lrow][kc * 32 + kgrp * 8];
#pragma unroll
    for (int nd = 0; nd < 8; ++nd)
#pragma unroll
      for (int kc = 0; kc < 2; ++kc) {
        s16x8 vb = *(const s16x8*)&Vl[vbuf][nd * 16 + lrow]
                                     [((kc * 4 + kgrp) ^ (lrow & 7)) * 8];
#pragma unroll
        for (int f = 0; f < 2; ++f) acc[f][nd] = MFMA(pa[f][kc], vb, acc[f][nd]);
      }
  };

  // prologue: K0->Kl0, K1->Kl1, V0->Vl0; QK(0)->scA
  STAGE_K(0, 0);
  STAGE_K(1, 64);
  STAGE_V(0, 0);
  __syncthreads();
  QK(0, scA);
  __syncthreads();  // all waves done reading Kl[0] before half-A stages it

  for (int tt = 0; tt < NT; tt += 2) {
    // half A: tile tt (scA), next tile tt+1 -> scB
    if (tt + 2 < NT) STAGE_K(0, (tt + 2) * 64);
    if (tt + 1 < NT) STAGE_V(1, (tt + 1) * 64);
    if (tt + 1 < NT) QK(1, scB);
    SPV(scA, 0);
    __syncthreads();
    // half B: tile tt+1 (scB), next tile tt+2 -> scA
    if (tt + 3 < NT) STAGE_K(1, (tt + 3) * 64);
    if (tt + 2 < NT) STAGE_V(0, (tt + 2) * 64);
    if (tt + 2 < NT) QK(0, scA);
    SPV(scB, 1);
    __syncthreads();
  }
#undef STAGE_K
#undef STAGE_V

  // epilogue: reduce l across kgrp (2 shfls), broadcast per acc-row, store
  float li[2][4];
#pragma unroll
  for (int f = 0; f < 2; ++f) {
    float lv = l_[f];
    lv += __shfl_xor(lv, 16, 64);
    lv += __shfl_xor(lv, 32, 64);
#pragma unroll
    for (int r = 0; r < 4; ++r) li[f][r] = 1.f / __shfl(lv, kgrp * 4 + r, 16);
  }
#pragma unroll
  for (int f = 0; f < 2; ++f)
#pragma unroll
    for (int nd = 0; nd < 8; ++nd)
#pragma unroll
      for (int r = 0; r < 4; ++r) {
        int row = qb * 256 + w * 32 + f * 16 + kgrp * 4 + r;
        O[((size_t)b * SS + row) * 2048 + h * HD + nd * 16 + lrow] =
            __float2bfloat16(acc[f][nd][r] * li[f][r]);
      }
}

// ---------------- launch ----------------

extern "C" void kernel_launch(void* const* d_in, const int* in_sizes, int n_in,
                              void* d_out, int out_size, void* d_ws, size_t ws_size,
                              hipStream_t stream) {
  const float* hs = (const float*)d_in[0];
  const float* Wqkv = (const float*)d_in[1];
  const float* Wo = (const float*)d_in[2];
  const float* ctx_k = (const float*)d_in[3];
  const float* ctx_v = (const float*)d_in[4];
  const int* pid = (const int*)d_in[5];
  float* out = (float*)d_out;
  char* ws = (char*)d_ws;

  bf16* Hb = (bf16*)(ws);                      // 16.78 MB (reused as attn_out)
  bf16* WqT = (bf16*)(ws + 16777216);          // 16.78 MB
  bf16* WoT = (bf16*)(ws + 33554432);          // 8.39 MB
  bf16* qkv = (bf16*)(ws + 41943040);          // 33.55 MB
  bf16* Qb = (bf16*)(ws + 75497472);           // 16.78 MB
  bf16* Kfull = (bf16*)(ws + 92274688);        // 25.17 MB
  bf16* Vt = (bf16*)(ws + 117440512);          // 25.17 MB
  float* cosT = (float*)(ws + 142606336);      // 256 KB
  float* sinT = (float*)(ws + 142606336 + 262144);
  bf16* attn = Hb;  // alias: Hb dead after QKV GEMM

  rope_table<<<256, 256, 0, stream>>>(pid, cosT, sinT);
  cvt_bf16<<<4096, 256, 0, stream>>>(hs, Hb);
  transpose_cvt<<<dim3(128, 64), 256, 0, stream>>>(Wqkv, WqT, HID, QKVN);
  transpose_cvt<<<dim3(64, 64), 256, 0, stream>>>(Wo, WoT, 2048, 2048);
  ctxk_copy<<<4096, 256, 0, stream>>>(ctx_k, Kfull);
  ctxv_transpose<<<dim3(64, 4, 32), 256, 0, stream>>>(ctx_v, Vt);
  gemm_bt<bf16><<<dim3(QKVN / 128, MROWS / 256), 512, 0, stream>>>(
      Hb, WqT, qkv, MROWS, QKVN, HID);
  rope_q<<<16384, 256, 0, stream>>>(qkv, cosT, sinT, Qb);
  rope_k<<<8192, 256, 0, stream>>>(qkv, cosT, sinT, Kfull);
  vt_from_qkv<<<dim3(32, 4, 32), 256, 0, stream>>>(qkv, Vt);
  flash_attn<<<256, 512, 0, stream>>>(Qb, Kfull, Vt, attn);
  gemm_bt<float><<<dim3(2048 / 128, MROWS / 256), 512, 0, stream>>>(
      attn, WoT, out, MROWS, 2048, HID);
}

// Round 9
// 357.768 us; speedup vs baseline: 1.0691x; 1.0691x over previous
//
#include <hip/hip_runtime.h>
#include <hip/hip_bf16.h>
#include <stdint.h>

#define NH 16
#define NKV 8
#define HD 128
#define BB 4
#define SS 1024
#define CTXL 2048
#define LT 3072
#define HID 2048
#define QKVN 4096
#define MROWS 4096

typedef __hip_bfloat16 bf16;
using f32x4 = __attribute__((ext_vector_type(4))) float;
using s16x8 = __attribute__((ext_vector_type(8))) short;

#define MFMA(a, b, c) __builtin_amdgcn_mfma_f32_16x16x32_bf16((a), (b), (c), 0, 0, 0)

__device__ __forceinline__ void gload_lds16(const void* g, void* l) {
  __builtin_amdgcn_global_load_lds((const __attribute__((address_space(1))) void*)g,
                                   (__attribute__((address_space(3))) void*)l, 16, 0, 0);
}

__device__ __forceinline__ void store_bf8(bf16* dst, const float* f) {
  bf16 tmp[8];
#pragma unroll
  for (int j = 0; j < 8; ++j) tmp[j] = __float2bfloat16(f[j]);
  __builtin_memcpy((void*)dst, (const void*)tmp, 16);
}

// ---------------- prep kernels ----------------

__global__ void cvt_bf16(const float* __restrict__ in, bf16* __restrict__ out) {
  size_t tid = (size_t)blockIdx.x * 256 + threadIdx.x;  // one thread per 8 elems
  const float4* p = (const float4*)(in + tid * 8);
  float4 a = p[0], b = p[1];
  float f[8] = {a.x, a.y, a.z, a.w, b.x, b.y, b.z, b.w};
  store_bf8(out + tid * 8, f);
}

// out[c][r] = (bf16) in[r][c]
__global__ void transpose_cvt(const float* __restrict__ in, bf16* __restrict__ out,
                              int R, int C) {
  __shared__ float tile[32][33];
  int c0 = blockIdx.x * 32, r0 = blockIdx.y * 32;
  int tx = threadIdx.x & 31, ty = threadIdx.x >> 5;
#pragma unroll
  for (int i = 0; i < 32; i += 8)
    tile[ty + i][tx] = in[(size_t)(r0 + ty + i) * C + c0 + tx];
  __syncthreads();
#pragma unroll
  for (int i = 0; i < 32; i += 8)
    out[(size_t)(c0 + ty + i) * R + r0 + tx] = __float2bfloat16(tile[tx][ty + i]);
}

// ctx_k [b][l][h][d] f32 -> K_full [b][h][l][d] bf16 (l < CTXL)
__global__ void ctxk_copy(const float* __restrict__ ck, bf16* __restrict__ Kf) {
  int tid = blockIdx.x * 256 + threadIdx.x;
  int d8 = tid & 15, l = (tid >> 4) & 2047, h = (tid >> 15) & 7, b = tid >> 18;
  const float* s = ck + (((size_t)b * CTXL + l) * NKV + h) * HD + d8 * 8;
  const float4* p = (const float4*)s;
  float4 a = p[0], bb = p[1];
  float f[8] = {a.x, a.y, a.z, a.w, bb.x, bb.y, bb.z, bb.w};
  store_bf8(Kf + (((size_t)(b * NKV + h)) * LT + l) * HD + d8 * 8, f);
}

// ctx_v [b][l][h][d] f32 -> V_T [b][h][d][l] bf16 (l < CTXL)
__global__ void ctxv_transpose(const float* __restrict__ cv, bf16* __restrict__ Vt) {
  __shared__ float tile[32][33];
  int l0 = blockIdx.x * 32, d0 = blockIdx.y * 32;
  int b = blockIdx.z >> 3, h = blockIdx.z & 7;
  int tx = threadIdx.x & 31, ty = threadIdx.x >> 5;
#pragma unroll
  for (int i = 0; i < 32; i += 8)
    tile[ty + i][tx] = cv[(((size_t)b * CTXL + l0 + ty + i) * NKV + h) * HD + d0 + tx];
  __syncthreads();
#pragma unroll
  for (int i = 0; i < 32; i += 8)
    Vt[(((size_t)(b * NKV + h)) * HD + d0 + ty + i) * LT + l0 + tx] =
        __float2bfloat16(tile[tx][ty + i]);
}

// qkv v-slice -> V_T tail (l = CTXL + s)
__global__ void vt_from_qkv(const bf16* __restrict__ qkv, bf16* __restrict__ Vt) {
  __shared__ float tile[32][33];
  int s0 = blockIdx.x * 32, d0 = blockIdx.y * 32;
  int b = blockIdx.z >> 3, h = blockIdx.z & 7;
  int tx = threadIdx.x & 31, ty = threadIdx.x >> 5;
#pragma unroll
  for (int i = 0; i < 32; i += 8)
    tile[ty + i][tx] = __bfloat162float(
        qkv[((size_t)b * SS + s0 + ty + i) * QKVN + 3072 + h * HD + d0 + tx]);
  __syncthreads();
#pragma unroll
  for (int i = 0; i < 32; i += 8)
    Vt[(((size_t)(b * NKV + h)) * HD + d0 + ty + i) * LT + CTXL + s0 + tx] =
        __float2bfloat16(tile[tx][ty + i]);
}

__global__ void rope_table(const int* __restrict__ pid, float* __restrict__ cosT,
                           float* __restrict__ sinT) {
  int tid = blockIdx.x * 256 + threadIdx.x;  // S*64
  int j = tid & 63, s = tid >> 6;
  int sec = (j < 8) ? 0 : (j < 16) ? 1 : (j < 40) ? 2 : 3;
  float pos = (float)pid[sec * SS + s];
  float inv = __expf(-(float)j * 0.14391156831212787f);  // ln(10000)/64
  float a = pos * inv;
  cosT[tid] = cosf(a);
  sinT[tid] = sinf(a);
}

__global__ void rope_q(const bf16* __restrict__ qkv, const float* __restrict__ cosT,
                       const float* __restrict__ sinT, bf16* __restrict__ Q) {
  int tid = blockIdx.x * 256 + threadIdx.x;
  int j = tid & 63, h = (tid >> 6) & 15, s = (tid >> 10) & 1023, b = tid >> 20;
  const bf16* src = qkv + ((size_t)b * SS + s) * QKVN + h * HD;
  float x1 = __bfloat162float(src[j]), x2 = __bfloat162float(src[j + 64]);
  float c = cosT[s * 64 + j], sn = sinT[s * 64 + j];
  bf16* dst = Q + (((size_t)(b * NH + h)) * SS + s) * HD;
  dst[j] = __float2bfloat16(x1 * c - x2 * sn);
  dst[j + 64] = __float2bfloat16(x2 * c + x1 * sn);
}

__global__ void rope_k(const bf16* __restrict__ qkv, const float* __restrict__ cosT,
                       const float* __restrict__ sinT, bf16* __restrict__ Kf) {
  int tid = blockIdx.x * 256 + threadIdx.x;
  int j = tid & 63, h = (tid >> 6) & 7, s = (tid >> 9) & 1023, b = tid >> 19;
  const bf16* src = qkv + ((size_t)b * SS + s) * QKVN + 2048 + h * HD;
  float x1 = __bfloat162float(src[j]), x2 = __bfloat162float(src[j + 64]);
  float c = cosT[s * 64 + j], sn = sinT[s * 64 + j];
  bf16* dst = Kf + (((size_t)(b * NKV + h)) * LT + CTXL + s) * HD;
  dst[j] = __float2bfloat16(x1 * c - x2 * sn);
  dst[j + 64] = __float2bfloat16(x2 * c + x1 * sn);
}

// ---------------- GEMM: C[M][N] = A[M][K] * BT[N][K]^T ----------------
// 256x128 tile, BK=64, 8 waves (4M x 2N), 512 threads. 3-buffer LDS (144 KB),
// prefetch depth 2, ONE barrier per K-tile, counted s_waitcnt vmcnt(6).
// XOR chunk swizzle both sides (rule 21). NEW: T1 XCD-aware bijective block
// swizzle (grid % 8 == 0 for both launches) for A/B panel L2 locality.

template <typename OT>
__global__ __launch_bounds__(512, 1) void gemm_bt(const bf16* __restrict__ A,
                                                  const bf16* __restrict__ BT,
                                                  OT* __restrict__ C, int M, int N,
                                                  int K) {
  __shared__ __attribute__((aligned(16))) bf16 lA[3][256][64];  // 96 KB
  __shared__ __attribute__((aligned(16))) bf16 lB[3][128][64];  // 48 KB
  const int t = threadIdx.x;
  const int lane = t & 63, w = t >> 6;
  const int wr = w >> 1, wc = w & 1;
  const int lrow = lane & 15, kgrp = lane >> 4;
  const int rchk = lrow & 7;  // read-side swizzle bits (frag row & 7)
  // T1: XCD-aware bijective remap (nwg % 8 == 0)
  const int lin = blockIdx.y * gridDim.x + blockIdx.x;
  const int qq = (gridDim.x * gridDim.y) >> 3;
  const int swz = (lin & 7) * qq + (lin >> 3);
  const int bx = swz % gridDim.x, by = swz / gridDim.x;
  const int m0 = by * 256, n0 = bx * 128;
  const int srow = lane >> 3;              // 0..7: row within 8-row group
  const int schk = (lane & 7) ^ srow;      // pre-swizzled source chunk
  const f32x4 fz = {0.f, 0.f, 0.f, 0.f};
  f32x4 acc[4][4];
#pragma unroll
  for (int i = 0; i < 4; ++i)
#pragma unroll
    for (int j = 0; j < 4; ++j) acc[i][j] = fz;
  const int NTK = K >> 6;

#define GSTAGE(ib, kt)                                                      \
  do {                                                                      \
    _Pragma("unroll") for (int c = 0; c < 4; ++c) {                         \
      int ra = c * 64 + w * 8 + srow;                                       \
      gload_lds16(A + (size_t)(m0 + ra) * K + (kt)*64 + schk * 8,           \
                  &lA[ib][c * 64 + w * 8][0]);                              \
    }                                                                       \
    _Pragma("unroll") for (int c = 0; c < 2; ++c) {                         \
      int rb = c * 64 + w * 8 + srow;                                       \
      gload_lds16(BT + (size_t)(n0 + rb) * K + (kt)*64 + schk * 8,          \
                  &lB[ib][c * 64 + w * 8][0]);                              \
    }                                                                       \
  } while (0)

  GSTAGE(0, 0);
  GSTAGE(1, 1);
  int ib = 0;
  for (int kt = 0; kt < NTK; ++kt) {
    if (kt + 1 < NTK)
      asm volatile("s_waitcnt vmcnt(6) lgkmcnt(0)" ::: "memory");
    else
      asm volatile("s_waitcnt vmcnt(0) lgkmcnt(0)" ::: "memory");
    __builtin_amdgcn_s_barrier();
    __builtin_amdgcn_sched_barrier(0);
    if (kt + 2 < NTK) {
      int ib2 = ib + 2;
      if (ib2 >= 3) ib2 -= 3;
      GSTAGE(ib2, kt + 2);
    }
#pragma unroll
    for (int kk = 0; kk < 2; ++kk) {
      s16x8 af[4], bf[4];
#pragma unroll
      for (int i = 0; i < 4; ++i)
        af[i] = *(const s16x8*)&lA[ib][wr * 64 + i * 16 + lrow]
                                     [(((kk << 2) + kgrp) ^ rchk) * 8];
#pragma unroll
      for (int j = 0; j < 4; ++j)
        bf[j] = *(const s16x8*)&lB[ib][wc * 64 + j * 16 + lrow]
                                     [(((kk << 2) + kgrp) ^ rchk) * 8];
      __builtin_amdgcn_s_setprio(1);
#pragma unroll
      for (int i = 0; i < 4; ++i)
#pragma unroll
        for (int j = 0; j < 4; ++j) acc[i][j] = MFMA(af[i], bf[j], acc[i][j]);
      __builtin_amdgcn_s_setprio(0);
    }
    ++ib;
    if (ib >= 3) ib = 0;
  }
#undef GSTAGE

#pragma unroll
  for (int i = 0; i < 4; ++i)
#pragma unroll
    for (int j = 0; j < 4; ++j)
#pragma unroll
      for (int r = 0; r < 4; ++r) {
        int row = m0 + wr * 64 + i * 16 + kgrp * 4 + r;
        int col = n0 + wc * 64 + j * 16 + lrow;
        float v = acc[i][j][r];
        if constexpr (sizeof(OT) == 2)
          C[(size_t)row * N + col] = __float2bfloat16(v);
        else
          C[(size_t)row * N + col] = v;
      }
}

// ---------------- flash attention ----------------
// 256 q-rows/block, 8 waves x 32 rows (2 row-frags), KVBLK=64, K/V double-
// buffered, ONE barrier per iteration (round-6 structure, 152 us). SWAPPED
// QK^T: sc = MFMA(K, Q) -> lane holds 16 scores of ONE q-row. Lane-local
// softmax; deferred l reduce; defer-max (T13). NEW: T5 s_setprio around the
// QK and PV MFMA clusters (waves drift between barriers -> role-split).
// XOR chunk swizzle both sides (rule 21): K chunk^(row&15), V chunk^(row&7).

#define PSTR 72  // P row stride in elements: 144B = 16B-aligned
#define NT 48    // LT / 64
// scale * log2(e): softmax computed in exp2 domain
#define SCALE2 0.1275174335919605f

__global__ __launch_bounds__(512, 2) void flash_attn(
    const bf16* __restrict__ Q, const bf16* __restrict__ Kf,
    const bf16* __restrict__ Vt, bf16* __restrict__ O) {
  __shared__ __attribute__((aligned(16))) bf16 Kl[2][64][128];      // 32 KB
  __shared__ __attribute__((aligned(16))) bf16 Vl[2][128][64];      // 32 KB
  __shared__ __attribute__((aligned(16))) bf16 P_lds[8][32][PSTR];  // 36 KB
  const int t = threadIdx.x, lane = t & 63, w = t >> 6;
  const int qb = blockIdx.x & 3, h = (blockIdx.x >> 2) & 15, b = blockIdx.x >> 6;
  const int hk = h >> 1;
  const int lrow = lane & 15, kgrp = lane >> 4;
  const bf16* Kp = Kf + (size_t)(b * NKV + hk) * LT * HD;
  const bf16* Vp = Vt + (size_t)(b * NKV + hk) * HD * LT;

  const bf16* Qp = Q + (((size_t)(b * NH + h)) * SS + qb * 256 + w * 32) * HD;
  s16x8 qf[2][4];
#pragma unroll
  for (int f = 0; f < 2; ++f)
#pragma unroll
    for (int kd = 0; kd < 4; ++kd)
      qf[f][kd] = *(const s16x8*)&Qp[(f * 16 + lrow) * HD + kd * 32 + kgrp * 8];

  const f32x4 fz = {0.f, 0.f, 0.f, 0.f};
  f32x4 acc[2][8];
#pragma unroll
  for (int f = 0; f < 2; ++f)
#pragma unroll
    for (int i = 0; i < 8; ++i) acc[f][i] = fz;
  // per-lane: m_/l_ track q-row (lane&15) of each frag; l_ is the partial
  // sum over this lane's kv subset (cross-kgrp reduce deferred to epilogue)
  float m_[2] = {-1e30f, -1e30f}, l_[2] = {0.f, 0.f};

  // staging geometry (8 waves, 512 threads)
#define STAGE_K(buf, l0)                                                        \
  do {                                                                          \
    _Pragma("unroll") for (int c = 0; c < 2; ++c) {                             \
      int row = w * 8 + c * 4 + (lane >> 4);                                    \
      gload_lds16(Kp + (size_t)((l0) + row) * HD + ((lane & 15) ^ (row & 15)) * 8, \
                  &Kl[buf][w * 8 + c * 4][0]);                                  \
    }                                                                           \
  } while (0)
#define STAGE_V(buf, l0)                                                        \
  do {                                                                          \
    _Pragma("unroll") for (int c = 0; c < 2; ++c) {                             \
      int d = w * 16 + c * 8 + (lane >> 3);                                     \
      gload_lds16(Vp + (size_t)d * LT + (l0) + ((lane & 7) ^ (d & 7)) * 8,      \
                  &Vl[buf][w * 16 + c * 8][0]);                                 \
    }                                                                           \
  } while (0)

  STAGE_K(0, 0);
  STAGE_V(0, 0);
  __syncthreads();

  for (int tt = 0; tt < NT; ++tt) {
    const int cur = tt & 1;
    if (tt + 1 < NT) {
      STAGE_K(cur ^ 1, (tt + 1) * 64);
      STAGE_V(cur ^ 1, (tt + 1) * 64);
    }

    // QK^T swapped: sc[f][cf][r] = score for q-row (lane&15) of frag f,
    // kv = cf*16 + kgrp*4 + r
    f32x4 sc[2][4];
#pragma unroll
    for (int f = 0; f < 2; ++f)
#pragma unroll
      for (int cf = 0; cf < 4; ++cf) sc[f][cf] = fz;
    __builtin_amdgcn_s_setprio(1);
#pragma unroll
    for (int cf = 0; cf < 4; ++cf)
#pragma unroll
      for (int kd = 0; kd < 4; ++kd) {
        s16x8 kb =
            *(const s16x8*)&Kl[cur][cf * 16 + lrow][((kd * 4 + kgrp) ^ lrow) * 8];
#pragma unroll
        for (int f = 0; f < 2; ++f) sc[f][cf] = MFMA(kb, qf[f][kd], sc[f][cf]);
      }
    __builtin_amdgcn_s_setprio(0);

    // lane-local max over this lane's 16 scores, then 2 wide shfls
    float mxv[2];
#pragma unroll
    for (int f = 0; f < 2; ++f) {
      float a0 = fmaxf(fmaxf(sc[f][0][0], sc[f][0][1]),
                       fmaxf(sc[f][0][2], sc[f][0][3]));
      float a1 = fmaxf(fmaxf(sc[f][1][0], sc[f][1][1]),
                       fmaxf(sc[f][1][2], sc[f][1][3]));
      float a2 = fmaxf(fmaxf(sc[f][2][0], sc[f][2][1]),
                       fmaxf(sc[f][2][2], sc[f][2][3]));
      float a3 = fmaxf(fmaxf(sc[f][3][0], sc[f][3][1]),
                       fmaxf(sc[f][3][2], sc[f][3][3]));
      float mx = fmaxf(fmaxf(a0, a1), fmaxf(a2, a3)) * SCALE2;
      mx = fmaxf(mx, __shfl_xor(mx, 16, 64));
      mx = fmaxf(mx, __shfl_xor(mx, 32, 64));
      mxv[f] = mx;
    }
    bool nb = (mxv[0] > m_[0] + 8.f) || (mxv[1] > m_[1] + 8.f);
    if (__any(nb)) {
#pragma unroll
      for (int f = 0; f < 2; ++f) {
        float mn = fmaxf(m_[f], mxv[f]);
        float so = exp2f(m_[f] - mn);
        m_[f] = mn;
        l_[f] *= so;
        float sob[4];
#pragma unroll
        for (int r = 0; r < 4; ++r) sob[r] = __shfl(so, kgrp * 4 + r, 16);
#pragma unroll
        for (int nd = 0; nd < 8; ++nd)
#pragma unroll
          for (int r = 0; r < 4; ++r) acc[f][nd][r] *= sob[r];
      }
    }
    // P: exp2, accumulate lane-partial l, pack 4 bf16 -> one b64 store per cf
#pragma unroll
    for (int f = 0; f < 2; ++f) {
      float lp = 0.f;
#pragma unroll
      for (int cf = 0; cf < 4; ++cf) {
        bf16 pk[4];
#pragma unroll
        for (int r = 0; r < 4; ++r) {
          float p = exp2f(sc[f][cf][r] * SCALE2 - m_[f]);
          lp += p;
          pk[r] = __float2bfloat16(p);
        }
        __builtin_memcpy((void*)&P_lds[w][f * 16 + lrow][cf * 16 + kgrp * 4], pk, 8);
      }
      l_[f] += lp;
    }

    // per-wave LDS: in-wave write->read ordering via lgkmcnt, no barrier
    s16x8 pa[2][2];
#pragma unroll
    for (int f = 0; f < 2; ++f)
#pragma unroll
      for (int kc = 0; kc < 2; ++kc)
        pa[f][kc] = *(const s16x8*)&P_lds[w][f * 16 + lrow][kc * 32 + kgrp * 8];

    // PV: each vb fragment feeds both row-frags
    __builtin_amdgcn_s_setprio(1);
#pragma unroll
    for (int nd = 0; nd < 8; ++nd)
#pragma unroll
      for (int kc = 0; kc < 2; ++kc) {
        s16x8 vb = *(const s16x8*)&Vl[cur][nd * 16 + lrow]
                                     [((kc * 4 + kgrp) ^ (lrow & 7)) * 8];
#pragma unroll
        for (int f = 0; f < 2; ++f) acc[f][nd] = MFMA(pa[f][kc], vb, acc[f][nd]);
      }
    __builtin_amdgcn_s_setprio(0);
    __syncthreads();  // drains stage(tt+1) DMA; protects bufs for next iter
  }
#undef STAGE_K
#undef STAGE_V

  // epilogue: reduce l across kgrp (2 shfls), broadcast per acc-row, store
  float li[2][4];
#pragma unroll
  for (int f = 0; f < 2; ++f) {
    float lv = l_[f];
    lv += __shfl_xor(lv, 16, 64);
    lv += __shfl_xor(lv, 32, 64);
#pragma unroll
    for (int r = 0; r < 4; ++r) li[f][r] = 1.f / __shfl(lv, kgrp * 4 + r, 16);
  }
#pragma unroll
  for (int f = 0; f < 2; ++f)
#pragma unroll
    for (int nd = 0; nd < 8; ++nd)
#pragma unroll
      for (int r = 0; r < 4; ++r) {
        int row = qb * 256 + w * 32 + f * 16 + kgrp * 4 + r;
        O[((size_t)b * SS + row) * 2048 + h * HD + nd * 16 + lrow] =
            __float2bfloat16(acc[f][nd][r] * li[f][r]);
      }
}

// ---------------- launch ----------------

extern "C" void kernel_launch(void* const* d_in, const int* in_sizes, int n_in,
                              void* d_out, int out_size, void* d_ws, size_t ws_size,
                              hipStream_t stream) {
  const float* hs = (const float*)d_in[0];
  const float* Wqkv = (const float*)d_in[1];
  const float* Wo = (const float*)d_in[2];
  const float* ctx_k = (const float*)d_in[3];
  const float* ctx_v = (const float*)d_in[4];
  const int* pid = (const int*)d_in[5];
  float* out = (float*)d_out;
  char* ws = (char*)d_ws;

  bf16* Hb = (bf16*)(ws);                      // 16.78 MB (reused as attn_out)
  bf16* WqT = (bf16*)(ws + 16777216);          // 16.78 MB
  bf16* WoT = (bf16*)(ws + 33554432);          // 8.39 MB
  bf16* qkv = (bf16*)(ws + 41943040);          // 33.55 MB
  bf16* Qb = (bf16*)(ws + 75497472);           // 16.78 MB
  bf16* Kfull = (bf16*)(ws + 92274688);        // 25.17 MB
  bf16* Vt = (bf16*)(ws + 117440512);          // 25.17 MB
  float* cosT = (float*)(ws + 142606336);      // 256 KB
  float* sinT = (float*)(ws + 142606336 + 262144);
  bf16* attn = Hb;  // alias: Hb dead after QKV GEMM

  rope_table<<<256, 256, 0, stream>>>(pid, cosT, sinT);
  cvt_bf16<<<4096, 256, 0, stream>>>(hs, Hb);
  transpose_cvt<<<dim3(128, 64), 256, 0, stream>>>(Wqkv, WqT, HID, QKVN);
  transpose_cvt<<<dim3(64, 64), 256, 0, stream>>>(Wo, WoT, 2048, 2048);
  ctxk_copy<<<4096, 256, 0, stream>>>(ctx_k, Kfull);
  ctxv_transpose<<<dim3(64, 4, 32), 256, 0, stream>>>(ctx_v, Vt);
  gemm_bt<bf16><<<dim3(QKVN / 128, MROWS / 256), 512, 0, stream>>>(
      Hb, WqT, qkv, MROWS, QKVN, HID);
  rope_q<<<16384, 256, 0, stream>>>(qkv, cosT, sinT, Qb);
  rope_k<<<8192, 256, 0, stream>>>(qkv, cosT, sinT, Kfull);
  vt_from_qkv<<<dim3(32, 4, 32), 256, 0, stream>>>(qkv, Vt);
  flash_attn<<<256, 512, 0, stream>>>(Qb, Kfull, Vt, attn);
  gemm_bt<float><<<dim3(2048 / 128, MROWS / 256), 512, 0, stream>>>(
      attn, WoT, out, MROWS, 2048, HID);
}